// Round 4
// baseline (125.677 us; speedup 1.0000x reference)
//
#include <hip/hip_runtime.h>

#define H 128
#define EPS 1e-12f

static __device__ __forceinline__ float bf_lo(unsigned int v) {
    return __uint_as_float(v << 16);
}
static __device__ __forceinline__ float bf_hi(unsigned int v) {
    return __uint_as_float(v & 0xFFFF0000u);
}
static __device__ __forceinline__ unsigned int f2bf_rne(float f) {
    unsigned int u = __float_as_uint(f);
    return (u + 0x7FFFu + ((u >> 16) & 1u)) >> 16;
}

// sum over 8 bf16 pairs with diag d folded in
static __device__ __forceinline__ float dot8(uint4 a, uint4 b,
                                             float4 d0, float4 d1, float p) {
    p = fmaf(bf_lo(a.x) * d0.x, bf_lo(b.x), p);
    p = fmaf(bf_hi(a.x) * d0.y, bf_hi(b.x), p);
    p = fmaf(bf_lo(a.y) * d0.z, bf_lo(b.y), p);
    p = fmaf(bf_hi(a.y) * d0.w, bf_hi(b.y), p);
    p = fmaf(bf_lo(a.z) * d1.x, bf_lo(b.z), p);
    p = fmaf(bf_hi(a.z) * d1.y, bf_hi(b.z), p);
    p = fmaf(bf_lo(a.w) * d1.z, bf_lo(b.w), p);
    p = fmaf(bf_hi(a.w) * d1.w, bf_hi(b.w), p);
    return p;
}

// Normalize each row to unit L2 norm, quantize to bf16, write 256B/row pool.
// One 64-lane wave per row. Raw emb read is one-pass streaming -> nontemporal
// (scalar float loads: the builtin rejects HIP vector types).
__global__ void norm_quant_kernel(const float* __restrict__ emb,
                                  unsigned int* __restrict__ pool,
                                  int n_nodes) {
    int row = blockIdx.x * (blockDim.x >> 6) + (threadIdx.x >> 6);
    if (row >= n_nodes) return;
    int lane = threadIdx.x & 63;
    const float* p = emb + (size_t)row * H + lane * 2;
    float vx = __builtin_nontemporal_load(p);
    float vy = __builtin_nontemporal_load(p + 1);
    float ss = vx * vx + vy * vy;
#pragma unroll
    for (int off = 32; off; off >>= 1) ss += __shfl_xor(ss, off);
    float inv = 1.0f / fmaxf(sqrtf(ss), EPS);
    unsigned int ua = f2bf_rne(vx * inv);
    unsigned int ub = f2bf_rne(vy * inv);
    pool[(size_t)row * 64 + lane] = ua | (ub << 16);
}

// 8 lanes/edge (32B per lane), 2 edge-batches per wave-iteration:
// 16 edges/wave/iter, 8 independent 16B gathers in flight per lane.
__global__ void edge_dot_bf16_kernel(const uint4* __restrict__ pool,
                                     const int* __restrict__ src,
                                     const int* __restrict__ dst,
                                     const float* __restrict__ d,
                                     const float* __restrict__ scale,
                                     float* __restrict__ out,
                                     int n_edges) {
    int lane = threadIdx.x & 63;
    int sub  = lane >> 3;   // 0..7: which edge within a batch
    int q    = lane & 7;    // 32B chunk within the 256B row

    // d elements 16q .. 16q+15, loaded once into registers
    float4 dv0 = ((const float4*)d)[q * 4 + 0];
    float4 dv1 = ((const float4*)d)[q * 4 + 1];
    float4 dv2 = ((const float4*)d)[q * 4 + 2];
    float4 dv3 = ((const float4*)d)[q * 4 + 3];
    float sc = scale[0];

    int waveId = (blockIdx.x * blockDim.x + threadIdx.x) >> 6;
    int nWaves = (gridDim.x * blockDim.x) >> 6;
    int last = n_edges - 1;

    for (int ebase = waveId * 16; ebase < n_edges; ebase += nWaves * 16) {
        int e0 = ebase + sub;
        int e1 = ebase + 8 + sub;
        bool w0 = (e0 < n_edges);
        bool w1 = (e1 < n_edges);
        int c0 = w0 ? e0 : last;
        int c1 = w1 ? e1 : last;

        int s0 = __builtin_nontemporal_load(src + c0);
        int t0 = __builtin_nontemporal_load(dst + c0);
        int s1 = __builtin_nontemporal_load(src + c1);
        int t1 = __builtin_nontemporal_load(dst + c1);

        // issue all 8 gathers before any compute
        const uint4* pa0 = pool + (size_t)s0 * 16 + q * 2;
        const uint4* pb0 = pool + (size_t)t0 * 16 + q * 2;
        const uint4* pa1 = pool + (size_t)s1 * 16 + q * 2;
        const uint4* pb1 = pool + (size_t)t1 * 16 + q * 2;
        uint4 a00 = pa0[0];
        uint4 a01 = pa0[1];
        uint4 b00 = pb0[0];
        uint4 b01 = pb0[1];
        uint4 a10 = pa1[0];
        uint4 a11 = pa1[1];
        uint4 b10 = pb1[0];
        uint4 b11 = pb1[1];

        float p0 = dot8(a00, b00, dv0, dv1, 0.0f);
        p0 = dot8(a01, b01, dv2, dv3, p0);
        float p1 = dot8(a10, b10, dv0, dv1, 0.0f);
        p1 = dot8(a11, b11, dv2, dv3, p1);

        // reduce across the 8 lanes of each edge group
        p0 += __shfl_xor(p0, 1);
        p1 += __shfl_xor(p1, 1);
        p0 += __shfl_xor(p0, 2);
        p1 += __shfl_xor(p1, 2);
        p0 += __shfl_xor(p0, 4);
        p1 += __shfl_xor(p1, 4);

        if (q == 0) {
            if (w0) __builtin_nontemporal_store(p0 * sc, out + e0);
            if (w1) __builtin_nontemporal_store(p1 * sc, out + e1);
        }
    }
}

// ---------------- fallback f32 path (proven R1) ----------------

__global__ void inv_norm_kernel(const float* __restrict__ emb,
                                float* __restrict__ inv,
                                int n_nodes) {
    int row = blockIdx.x * (blockDim.x >> 6) + (threadIdx.x >> 6);
    if (row >= n_nodes) return;
    int lane = threadIdx.x & 63;
    const float2* p = (const float2*)(emb + (size_t)row * H);
    float2 v = p[lane];
    float ss = v.x * v.x + v.y * v.y;
#pragma unroll
    for (int off = 32; off; off >>= 1) ss += __shfl_xor(ss, off);
    if (lane == 0) inv[row] = 1.0f / fmaxf(sqrtf(ss), EPS);
}

__global__ void edge_dot_kernel(const float* __restrict__ emb,
                                const float* __restrict__ inv,
                                const int* __restrict__ src,
                                const int* __restrict__ dst,
                                const float* __restrict__ d,
                                const float* __restrict__ scale,
                                float* __restrict__ out,
                                int n_edges) {
    int edge = blockIdx.x * (blockDim.x >> 6) + (threadIdx.x >> 6);
    if (edge >= n_edges) return;
    int lane = threadIdx.x & 63;
    int s = src[edge];
    int t = dst[edge];
    const float2* ps = (const float2*)(emb + (size_t)s * H);
    const float2* pt = (const float2*)(emb + (size_t)t * H);
    float2 dv = ((const float2*)d)[lane];
    float2 a = ps[lane];
    float2 b = pt[lane];
    float p = a.x * dv.x * b.x + a.y * dv.y * b.y;
#pragma unroll
    for (int off = 32; off; off >>= 1) p += __shfl_xor(p, off);
    if (lane == 0) out[edge] = p * inv[s] * inv[t] * scale[0];
}

extern "C" void kernel_launch(void* const* d_in, const int* in_sizes, int n_in,
                              void* d_out, int out_size, void* d_ws, size_t ws_size,
                              hipStream_t stream) {
    const float* emb   = (const float*)d_in[0];
    const int*   src   = (const int*)d_in[1];
    const int*   dst   = (const int*)d_in[2];
    const float* d     = (const float*)d_in[3];
    const float* scale = (const float*)d_in[4];
    float* out = (float*)d_out;

    int n_nodes = in_sizes[0] / H;
    int n_edges = in_sizes[1];

    size_t pool_bytes = (size_t)n_nodes * H * 2;  // bf16 pool

    if (ws_size >= pool_bytes) {
        unsigned int* pool = (unsigned int*)d_ws;

        int blocks1 = (n_nodes + 3) / 4;  // 4 rows per 256-thread block
        norm_quant_kernel<<<blocks1, 256, 0, stream>>>(emb, pool, n_nodes);

        // 2048 blocks x 4 waves x 16 edges = 131072 edges per sweep
        int blocks2 = 2048;
        edge_dot_bf16_kernel<<<blocks2, 256, 0, stream>>>(
            (const uint4*)pool, src, dst, d, scale, out, n_edges);
    } else {
        float* inv = (float*)d_ws;
        int blocks1 = (n_nodes + 3) / 4;
        inv_norm_kernel<<<blocks1, 256, 0, stream>>>(emb, inv, n_nodes);
        int blocks2 = (n_edges + 3) / 4;
        edge_dot_kernel<<<blocks2, 256, 0, stream>>>(emb, inv, src, dst, d,
                                                     scale, out, n_edges);
    }
}